// Round 7
// baseline (327.534 us; speedup 1.0000x reference)
//
#include <hip/hip_runtime.h>
#include <hip/hip_fp16.h>
#include <type_traits>

// Buckets: 512 nodes each, up to 256 buckets (nn <= 131072).
#define NBK 256
#define BSHIFT 9
#define NPB 512

template <int N> struct alignas(4 * N) HVec { __half2 v[N]; };

typedef _Float16 half8 __attribute__((ext_vector_type(8)));
typedef float f32x4 __attribute__((ext_vector_type(4)));

// ---- A1: per-bucket edge histogram ----
__global__ __launch_bounds__(256) void histA_k(const int* __restrict__ dst, int ne,
                                               int* __restrict__ gcount) {
    __shared__ int h[NBK];
    for (int i = threadIdx.x; i < NBK; i += 256) h[i] = 0;
    __syncthreads();
    int e0 = blockIdx.x * 4096;
    int e1 = min(e0 + 4096, ne);
    for (int e = e0 + (int)threadIdx.x; e < e1; e += 256)
        atomicAdd(&h[dst[e] >> BSHIFT], 1);
    __syncthreads();
    for (int i = threadIdx.x; i < NBK; i += 256)
        if (h[i]) atomicAdd(&gcount[i], h[i]);
}

// ---- A2: exclusive scan of PADDED bucket sizes -> bases + cursors ----
// Padded size = 4-aligned real count + 3*NPB slack (worst-case per-node pad4).
__global__ __launch_bounds__(256) void scanB_k(const int* __restrict__ gcount,
                                               int* __restrict__ gbase,
                                               int* __restrict__ cursor) {
    __shared__ int sh[NBK];
    int t = threadIdx.x;
    int v = ((gcount[t] + 3) & ~3) + 3 * NPB;   // 4-aligned upper bound
    sh[t] = v;
    __syncthreads();
    for (int d = 1; d < NBK; d <<= 1) {
        int u = (t >= d) ? sh[t - d] : 0;
        __syncthreads();
        sh[t] += u;
        __syncthreads();
    }
    int ex = sh[t] - v;
    gbase[t] = ex;
    cursor[t] = ex;
}

// ---- A3: partition edges into bucket regions, packed (dst_local<<17)|src ----
__global__ __launch_bounds__(512) void partA_k(const int* __restrict__ src,
                                               const int* __restrict__ dst,
                                               int* __restrict__ cursor,
                                               int* __restrict__ bucketed, int ne) {
    constexpr int EPB = 8192;
    __shared__ int hist[NBK], lofs[NBK + 1], lcur[NBK], gbs[NBK], sc[NBK];
    __shared__ int stage[EPB];
    int t = threadIdx.x;
    int e0 = blockIdx.x * EPB;
    int e1 = min(e0 + EPB, ne);
    int cnt = e1 - e0;
    for (int i = t; i < NBK; i += 512) hist[i] = 0;
    __syncthreads();
    int sv[16], dv[16];
#pragma unroll
    for (int k = 0; k < 16; k++) {
        int e = e0 + t + k * 512;
        int s = 0, d = 0;
        if (e < e1) {
            s = src[e];
            d = dst[e];
            atomicAdd(&hist[d >> BSHIFT], 1);
        }
        sv[k] = s;
        dv[k] = d;
    }
    __syncthreads();
    if (t < NBK) sc[t] = hist[t];
    __syncthreads();
    for (int d = 1; d < NBK; d <<= 1) {
        int u = 0;
        if (t < NBK && t >= d) u = sc[t - d];
        __syncthreads();
        if (t < NBK) sc[t] += u;
        __syncthreads();
    }
    if (t < NBK) {
        int ex = sc[t] - hist[t];
        lofs[t] = ex;
        lcur[t] = ex;
        gbs[t] = hist[t] ? atomicAdd(&cursor[t], hist[t]) : 0;
    }
    if (t == 0) lofs[NBK] = cnt;
    __syncthreads();
#pragma unroll
    for (int k = 0; k < 16; k++) {
        int e = e0 + t + k * 512;
        if (e < e1) {
            int b = dv[k] >> BSHIFT;
            int q = atomicAdd(&lcur[b], 1);
            stage[q] = ((dv[k] & (NPB - 1)) << 17) | sv[k];
        }
    }
    __syncthreads();
    for (int idx = t; idx < cnt; idx += 512) {
        int lo = 0, hi = NBK;
        while (hi - lo > 1) {
            int mid = (lo + hi) >> 1;
            if (lofs[mid] <= idx) lo = mid; else hi = mid;
        }
        bucketed[gbs[lo] + (idx - lofs[lo])] = stage[idx];
    }
}

// ---- B: per-bucket CSR finalize with per-node pad4 (dummy src = nn -> zero row) ----
// Writes rowbeg/rend (padded, 4-aligned segments) + dinv. All global io coalesced.
__global__ __launch_bounds__(1024) void csrB_k(const int* __restrict__ bucketed,
                                               const int* __restrict__ gbase,
                                               const int* __restrict__ gcount,
                                               int* __restrict__ csr,
                                               int* __restrict__ rowbeg,
                                               int* __restrict__ rend,
                                               float* __restrict__ dinv, int nn) {
    constexpr int CAP = 10240;
    __shared__ int cnt[NPB], ofs[NPB], cur[NPB];
    __shared__ int stage[CAP];
    __shared__ int ptot_s;
    int t = threadIdx.x;
    int b = blockIdx.x;
    int beg = gbase[b];
    int m = gcount[b];
    if (t < NPB) cnt[t] = 0;
    __syncthreads();
    for (int i = t; i < m; i += 1024)
        atomicAdd(&cnt[bucketed[beg + i] >> 17], 1);
    __syncthreads();
    int v = 0, pv = 0;
    if (t < NPB) { v = cnt[t]; pv = (v + 3) & ~3; ofs[t] = pv; }
    __syncthreads();
    for (int d = 1; d < NPB; d <<= 1) {
        int u = 0;
        if (t < NPB && t >= d) u = ofs[t - d];
        __syncthreads();
        if (t < NPB) ofs[t] += u;
        __syncthreads();
    }
    if (t == NPB - 1) ptot_s = ofs[t];
    int ex = 0;
    if (t < NPB) {
        ex = ofs[t] - pv;
        cur[t] = ex;
        int node = b * NPB + t;
        if (node < nn) {
            rowbeg[node] = beg + ex;
            rend[node]   = beg + ex + pv;
            dinv[node] = rsqrtf((float)(v + 1));   // +1 self-loop
        }
    }
    __syncthreads();
    int ptot = ptot_s;
    if (ptot <= CAP) {
        for (int i = t; i < m; i += 1024) {
            int e = bucketed[beg + i];
            int p = atomicAdd(&cur[e >> 17], 1);
            stage[p] = e & 0x1FFFF;
        }
        __syncthreads();
        if (t < NPB)
            for (int k = v; k < pv; k++) stage[ex + k] = nn;   // dummy pads
        __syncthreads();
        for (int i = t; i < ptot; i += 1024) csr[beg + i] = stage[i];
    } else {  // defensive fallback
        for (int i = t; i < m; i += 1024) {
            int e = bucketed[beg + i];
            int p = atomicAdd(&cur[e >> 17], 1);
            csr[beg + p] = e & 0x1FFFF;
        }
        __syncthreads();
        if (t < NPB)
            for (int k = v; k < pv; k++) csr[beg + ex + k] = nn;
    }
}

// ---- W prep: transpose+fp16 WT1/WT2; zero the 8 dummy rows hC[c][nn][:] ----
__global__ void prepW_k(const float* __restrict__ W1, const float* __restrict__ W2,
                        _Float16* __restrict__ WT1, _Float16* __restrict__ WT2,
                        _Float16* __restrict__ hC, int nn) {
    int i = blockIdx.x * blockDim.x + threadIdx.x;
    if (i < 128 * 128) {
        int k = i >> 7, j = i & 127;
        WT1[j * 128 + k] = (_Float16)W1[i];
    }
    int i2 = i - 128 * 128;
    if (i2 >= 0 && i2 < 128 * 64) {
        int k = i2 >> 6, j = i2 & 63;
        WT2[j * 128 + k] = (_Float16)W2[i2];
    }
    int i3 = i - (128 * 128 + 128 * 64);
    if (i3 >= 0 && i3 < 8 * 16) {
        int c = i3 >> 4, j = i3 & 15;
        hC[(size_t)c * ((size_t)(nn + 1) * 16) + (size_t)nn * 16 + j] = (_Float16)0.f;
    }
}

// ---------------- MFMA dense transform: H = X @ W, CHUNKED output ----------------
// One wave per 16-row tile. Output: H[c][node][16] fp16, chunk stride (nn+1)*16
// (row nn is the zeroed dummy). SCALE multiplies rows by dinv (h' = dinv .* XW).
template <int NO, bool SCALE, typename XT>
__global__ __launch_bounds__(256) void gemm_mfma_k(const XT* __restrict__ X,
                                                   const _Float16* __restrict__ WT,
                                                   const float* __restrict__ dinv,
                                                   _Float16* __restrict__ H, int nrows) {
    constexpr int K = 128;
    constexpr int NCT = NO / 16;
    int wv = (int)((blockIdx.x * (size_t)blockDim.x + threadIdx.x) >> 6);
    int r0 = wv * 16;
    if (r0 >= nrows) return;
    int lane = threadIdx.x & 63;
    int lr = lane & 15;          // A-row / D-col
    int kg = lane >> 4;          // k-group
    int rg = r0 + lr;
    if (rg >= nrows) rg = nrows - 1;   // clamp (stores are guarded)
    size_t cs = (size_t)(nrows + 1) * 16;    // chunk stride (incl. dummy row)

    half8 a[4];
    if constexpr (std::is_same<XT, float>::value) {
#pragma unroll
        for (int ks = 0; ks < 4; ks++) {
            const float* px = X + (size_t)rg * K + ks * 32 + kg * 8;
            float4 x0 = *(const float4*)px;
            float4 x1 = *(const float4*)(px + 4);
            half8 vv;
            vv[0] = (_Float16)x0.x; vv[1] = (_Float16)x0.y;
            vv[2] = (_Float16)x0.z; vv[3] = (_Float16)x0.w;
            vv[4] = (_Float16)x1.x; vv[5] = (_Float16)x1.y;
            vv[6] = (_Float16)x1.z; vv[7] = (_Float16)x1.w;
            a[ks] = vv;
        }
    } else {
#pragma unroll
        for (int ks = 0; ks < 4; ks++)
            a[ks] = *(const half8*)(X + (size_t)rg * K + ks * 32 + kg * 8);
    }

    f32x4 acc[NCT];
#pragma unroll
    for (int ct = 0; ct < NCT; ct++) acc[ct] = (f32x4){0.f, 0.f, 0.f, 0.f};
#pragma unroll
    for (int ct = 0; ct < NCT; ct++) {
#pragma unroll
        for (int ks = 0; ks < 4; ks++) {
            half8 b = *(const half8*)(WT + (size_t)(ct * 16 + lr) * K + ks * 32 + kg * 8);
            acc[ct] = __builtin_amdgcn_mfma_f32_16x16x32_f16(a[ks], b, acc[ct], 0, 0, 0);
        }
    }
#pragma unroll
    for (int i = 0; i < 4; i++) {
        int rr = r0 + kg * 4 + i;
        if (rr < nrows) {
            float s = SCALE ? dinv[rr] : 1.f;
            _Float16* hp = H + (size_t)rr * 16 + lr;
#pragma unroll
            for (int ct = 0; ct < NCT; ct++)
                hp[ct * cs] = (_Float16)(acc[ct][i] * s);
        }
    }
}

// ---------------- chunked aggregation v2: lane-owns-node ----------------
// HC[c][node][16] fp16, chunk slice 3.2MB -> XCD-L2-resident via chunk=blockIdx%NCHUNK.
// Lane owns one node: acc[16] f32 in VGPRs, NO cross-lane reduction.
// Edge loop: 4 edges/iter via int4 csr load (segments pad4'd with dummy src=nn -> zero row),
// 4 independent 32B gathers -> MLP ~8. rowbeg/rend/dinv/self/out all coalesced.
template <int NF, int NCHUNK, bool RELU, bool OUTSCALE, typename OutT>
__global__ __launch_bounds__(256) void aggc2_k(const __half* __restrict__ HC,
                                               const int* __restrict__ rowbeg,
                                               const int* __restrict__ rend,
                                               const int* __restrict__ csr,
                                               const float* __restrict__ dinv,
                                               const float* __restrict__ bias,
                                               OutT* __restrict__ Out, int nn) {
    constexpr int CF = 16;
    int chunk = (int)(blockIdx.x % NCHUNK);
    int nid = (int)(blockIdx.x / NCHUNK) * 256 + (int)threadIdx.x;
    if (nid >= nn) return;
    const __half* Hc = HC + (size_t)chunk * ((size_t)(nn + 1) * CF);

    float acc[CF];
#pragma unroll
    for (int j = 0; j < CF; j++) acc[j] = 0.f;

    int i = rowbeg[nid], end = rend[nid];
    for (; i < end; i += 4) {
        int4 s4 = *(const int4*)(csr + i);
        HVec<8> r0 = *(const HVec<8>*)(Hc + (size_t)s4.x * CF);
        HVec<8> r1 = *(const HVec<8>*)(Hc + (size_t)s4.y * CF);
        HVec<8> r2 = *(const HVec<8>*)(Hc + (size_t)s4.z * CF);
        HVec<8> r3 = *(const HVec<8>*)(Hc + (size_t)s4.w * CF);
#pragma unroll
        for (int q = 0; q < 8; q++) {
            __half2 p01 = __hadd2(r0.v[q], r1.v[q]);   // one fp16 pair-add level
            __half2 p23 = __hadd2(r2.v[q], r3.v[q]);
            float2 f01 = __half22float2(p01);
            float2 f23 = __half22float2(p23);
            acc[2 * q + 0] += f01.x + f23.x;
            acc[2 * q + 1] += f01.y + f23.y;
        }
    }
    // self-loop (h'[nid], already dinv-scaled)
    HVec<8> hs = *(const HVec<8>*)(Hc + (size_t)nid * CF);
    float dn = dinv[nid];
    float r[CF];
#pragma unroll
    for (int q = 0; q < 8; q++) {
        float2 f = __half22float2(hs.v[q]);
        r[2 * q + 0] = (acc[2 * q + 0] + f.x) * dn + bias[chunk * CF + 2 * q + 0];
        r[2 * q + 1] = (acc[2 * q + 1] + f.y) * dn + bias[chunk * CF + 2 * q + 1];
    }
#pragma unroll
    for (int j = 0; j < CF; j++) {
        if (RELU) r[j] = fmaxf(r[j], 0.f);
        if (OUTSCALE) r[j] *= dn;      // pre-scale for next layer's aggregation
    }
    if constexpr (std::is_same<OutT, __half>::value) {
        HVec<8> o;
#pragma unroll
        for (int q = 0; q < 8; q++) o.v[q] = __floats2half2_rn(r[2 * q], r[2 * q + 1]);
        *(HVec<8>*)(Out + (size_t)nid * NF + chunk * CF) = o;   // row-major fp16
    } else {
        float* op = Out + (size_t)nid * NF + chunk * CF;
#pragma unroll
        for (int q = 0; q < 4; q++) {
            float4 o;
            o.x = r[4 * q + 0]; o.y = r[4 * q + 1];
            o.z = r[4 * q + 2]; o.w = r[4 * q + 3];
            *(float4*)(op + 4 * q) = o;
        }
    }
}

// ---------------- launch ----------------

extern "C" void kernel_launch(void* const* d_in, const int* in_sizes, int n_in,
                              void* d_out, int out_size, void* d_ws, size_t ws_size,
                              hipStream_t stream) {
    const float* x  = (const float*)d_in[0];
    const int* ei   = (const int*)d_in[1];
    const float* W1 = (const float*)d_in[2];
    const float* b1 = (const float*)d_in[3];
    const float* W2 = (const float*)d_in[4];
    const float* b2 = (const float*)d_in[5];
    float* out = (float*)d_out;

    const int IN = 128, HID = 128;
    int nn = in_sizes[0] / IN;     // 100000
    int ne = in_sizes[1] / 2;      // 1600000
    const int* src = ei;
    const int* dst = ei + ne;
    int nbuckets = (nn + NPB - 1) / NPB;   // 196 (<= NBK)

    char* w = (char*)d_ws;
    size_t off = 0;
    auto take = [&](size_t bytes) -> void* {
        void* p = w + off;
        off = (off + bytes + 255) & ~(size_t)255;
        return p;
    };
    int*      gcount = (int*)take(NBK * 4);
    int*      gbase  = (int*)take(NBK * 4);
    int*      cursor = (int*)take(NBK * 4);
    int*      rowbeg = (int*)take((size_t)nn * 4);
    int*      rend   = (int*)take((size_t)nn * 4);
    float*    dinv   = (float*)take((size_t)nn * 4);
    int*      csr    = (int*)take(((size_t)ne + NBK * 1540) * 4);   // padded CSR
    _Float16* WT1    = (_Float16*)take(128 * 128 * 2);
    _Float16* WT2    = (_Float16*)take(64 * 128 * 2);
    _Float16* hC     = (_Float16*)take((size_t)(nn + 1) * 128 * 2); // 8 x [nn+1][16]
    __half*   h1     = (__half*)take((size_t)nn * HID * 2);         // row-major
    _Float16* h2C    = hC;                 // reuse: hC dead after agg1 (4 x [nn+1][16])
    int*      bucketed = (int*)hC;         // reuse: dead before prepW/gemm1 touch hC

    (void)ws_size; (void)n_in; (void)out_size;

    hipMemsetAsync(gcount, 0, NBK * 4, stream);

    int tb = 256;
    histA_k<<<(ne + 4095) / 4096, 256, 0, stream>>>(dst, ne, gcount);
    scanB_k<<<1, NBK, 0, stream>>>(gcount, gbase, cursor);
    partA_k<<<(ne + 8191) / 8192, 512, 0, stream>>>(src, dst, cursor, bucketed, ne);
    csrB_k<<<nbuckets, 1024, 0, stream>>>(bucketed, gbase, gcount, csr, rowbeg, rend, dinv, nn);
    prepW_k<<<(128 * 128 + 128 * 64 + 128 + tb - 1) / tb, tb, 0, stream>>>(W1, W2, WT1, WT2, hC, nn);

    int gblocks = ((nn + 15) / 16 + 3) / 4;   // 1 wave per 16 rows, 4 waves/block
    int ngrp256 = (nn + 255) / 256;           // node groups of 256 for aggc2

    // layer 1: hC = dinv .* (x @ W1)  [fp16, chunked] ; h1 = dinv .* relu(agg(hC) + b1)
    gemm_mfma_k<128, true, float><<<gblocks, tb, 0, stream>>>(x, WT1, dinv, hC, nn);
    aggc2_k<128, 8, true, true, __half><<<ngrp256 * 8, tb, 0, stream>>>(
        (const __half*)hC, rowbeg, rend, csr, dinv, b1, h1, nn);

    // layer 2: h2C = h1 @ W2 (already dinv-scaled)  [chunked] ; out = agg(h2C) + b2  [fp32]
    gemm_mfma_k<64, false, __half><<<gblocks, tb, 0, stream>>>(h1, WT2, dinv, h2C, nn);
    aggc2_k<64, 4, false, false, float><<<ngrp256 * 4, tb, 0, stream>>>(
        (const __half*)h2C, rowbeg, rend, csr, dinv, b2, out, nn);
}

// Round 8
// 249.573 us; speedup vs baseline: 1.3124x; 1.3124x over previous
//
#include <hip/hip_runtime.h>
#include <hip/hip_fp16.h>
#include <type_traits>

// Buckets: 512 nodes each, up to 256 buckets (nn <= 131072).
#define NBK 256
#define BSHIFT 9
#define NPB 512

template <int N> struct alignas(4 * N) HVec { __half2 v[N]; };

typedef _Float16 half8 __attribute__((ext_vector_type(8)));
typedef float f32x4 __attribute__((ext_vector_type(4)));

// ---- A1: per-bucket edge histogram ----
__global__ __launch_bounds__(256) void histA_k(const int* __restrict__ dst, int ne,
                                               int* __restrict__ gcount) {
    __shared__ int h[NBK];
    for (int i = threadIdx.x; i < NBK; i += 256) h[i] = 0;
    __syncthreads();
    int e0 = blockIdx.x * 4096;
    int e1 = min(e0 + 4096, ne);
    for (int e = e0 + (int)threadIdx.x; e < e1; e += 256)
        atomicAdd(&h[dst[e] >> BSHIFT], 1);
    __syncthreads();
    for (int i = threadIdx.x; i < NBK; i += 256)
        if (h[i]) atomicAdd(&gcount[i], h[i]);
}

// ---- A2: exclusive scan of PADDED bucket sizes -> bases + cursors ----
__global__ __launch_bounds__(256) void scanB_k(const int* __restrict__ gcount,
                                               int* __restrict__ gbase,
                                               int* __restrict__ cursor) {
    __shared__ int sh[NBK];
    int t = threadIdx.x;
    int v = ((gcount[t] + 3) & ~3) + 3 * NPB;   // 4-aligned upper bound
    sh[t] = v;
    __syncthreads();
    for (int d = 1; d < NBK; d <<= 1) {
        int u = (t >= d) ? sh[t - d] : 0;
        __syncthreads();
        sh[t] += u;
        __syncthreads();
    }
    int ex = sh[t] - v;
    gbase[t] = ex;
    cursor[t] = ex;
}

// ---- A3: partition edges into bucket regions, packed (dst_local<<17)|src ----
__global__ __launch_bounds__(512) void partA_k(const int* __restrict__ src,
                                               const int* __restrict__ dst,
                                               int* __restrict__ cursor,
                                               int* __restrict__ bucketed, int ne) {
    constexpr int EPB = 8192;
    __shared__ int hist[NBK], lofs[NBK + 1], lcur[NBK], gbs[NBK], sc[NBK];
    __shared__ int stage[EPB];
    int t = threadIdx.x;
    int e0 = blockIdx.x * EPB;
    int e1 = min(e0 + EPB, ne);
    int cnt = e1 - e0;
    for (int i = t; i < NBK; i += 512) hist[i] = 0;
    __syncthreads();
    int sv[16], dv[16];
#pragma unroll
    for (int k = 0; k < 16; k++) {
        int e = e0 + t + k * 512;
        int s = 0, d = 0;
        if (e < e1) {
            s = src[e];
            d = dst[e];
            atomicAdd(&hist[d >> BSHIFT], 1);
        }
        sv[k] = s;
        dv[k] = d;
    }
    __syncthreads();
    if (t < NBK) sc[t] = hist[t];
    __syncthreads();
    for (int d = 1; d < NBK; d <<= 1) {
        int u = 0;
        if (t < NBK && t >= d) u = sc[t - d];
        __syncthreads();
        if (t < NBK) sc[t] += u;
        __syncthreads();
    }
    if (t < NBK) {
        int ex = sc[t] - hist[t];
        lofs[t] = ex;
        lcur[t] = ex;
        gbs[t] = hist[t] ? atomicAdd(&cursor[t], hist[t]) : 0;
    }
    if (t == 0) lofs[NBK] = cnt;
    __syncthreads();
#pragma unroll
    for (int k = 0; k < 16; k++) {
        int e = e0 + t + k * 512;
        if (e < e1) {
            int b = dv[k] >> BSHIFT;
            int q = atomicAdd(&lcur[b], 1);
            stage[q] = ((dv[k] & (NPB - 1)) << 17) | sv[k];
        }
    }
    __syncthreads();
    for (int idx = t; idx < cnt; idx += 512) {
        int lo = 0, hi = NBK;
        while (hi - lo > 1) {
            int mid = (lo + hi) >> 1;
            if (lofs[mid] <= idx) lo = mid; else hi = mid;
        }
        bucketed[gbs[lo] + (idx - lofs[lo])] = stage[idx];
    }
}

// ---- B: per-bucket CSR finalize with per-node pad4 (dummy src = nn -> zero row) ----
__global__ __launch_bounds__(1024) void csrB_k(const int* __restrict__ bucketed,
                                               const int* __restrict__ gbase,
                                               const int* __restrict__ gcount,
                                               int* __restrict__ csr,
                                               int* __restrict__ rowbeg,
                                               int* __restrict__ rend,
                                               float* __restrict__ dinv, int nn) {
    constexpr int CAP = 10240;
    __shared__ int cnt[NPB], ofs[NPB], cur[NPB];
    __shared__ int stage[CAP];
    __shared__ int ptot_s;
    int t = threadIdx.x;
    int b = blockIdx.x;
    int beg = gbase[b];
    int m = gcount[b];
    if (t < NPB) cnt[t] = 0;
    __syncthreads();
    for (int i = t; i < m; i += 1024)
        atomicAdd(&cnt[bucketed[beg + i] >> 17], 1);
    __syncthreads();
    int v = 0, pv = 0;
    if (t < NPB) { v = cnt[t]; pv = (v + 3) & ~3; ofs[t] = pv; }
    __syncthreads();
    for (int d = 1; d < NPB; d <<= 1) {
        int u = 0;
        if (t < NPB && t >= d) u = ofs[t - d];
        __syncthreads();
        if (t < NPB) ofs[t] += u;
        __syncthreads();
    }
    if (t == NPB - 1) ptot_s = ofs[t];
    int ex = 0;
    if (t < NPB) {
        ex = ofs[t] - pv;
        cur[t] = ex;
        int node = b * NPB + t;
        if (node < nn) {
            rowbeg[node] = beg + ex;
            rend[node]   = beg + ex + pv;
            dinv[node] = rsqrtf((float)(v + 1));   // +1 self-loop
        }
    }
    __syncthreads();
    int ptot = ptot_s;
    if (ptot <= CAP) {
        for (int i = t; i < m; i += 1024) {
            int e = bucketed[beg + i];
            int p = atomicAdd(&cur[e >> 17], 1);
            stage[p] = e & 0x1FFFF;
        }
        __syncthreads();
        if (t < NPB)
            for (int k = v; k < pv; k++) stage[ex + k] = nn;   // dummy pads
        __syncthreads();
        for (int i = t; i < ptot; i += 1024) csr[beg + i] = stage[i];
    } else {  // defensive fallback
        for (int i = t; i < m; i += 1024) {
            int e = bucketed[beg + i];
            int p = atomicAdd(&cur[e >> 17], 1);
            csr[beg + p] = e & 0x1FFFF;
        }
        __syncthreads();
        if (t < NPB)
            for (int k = v; k < pv; k++) csr[beg + ex + k] = nn;
    }
}

// ---- W prep: transpose+fp16 WT1/WT2; zero the 8 dummy rows hC[c][nn][:] ----
__global__ void prepW_k(const float* __restrict__ W1, const float* __restrict__ W2,
                        _Float16* __restrict__ WT1, _Float16* __restrict__ WT2,
                        _Float16* __restrict__ hC, int nn) {
    int i = blockIdx.x * blockDim.x + threadIdx.x;
    if (i < 128 * 128) {
        int k = i >> 7, j = i & 127;
        WT1[j * 128 + k] = (_Float16)W1[i];
    }
    int i2 = i - 128 * 128;
    if (i2 >= 0 && i2 < 128 * 64) {
        int k = i2 >> 6, j = i2 & 63;
        WT2[j * 128 + k] = (_Float16)W2[i2];
    }
    int i3 = i - (128 * 128 + 128 * 64);
    if (i3 >= 0 && i3 < 8 * 16) {
        int c = i3 >> 4, j = i3 & 15;
        hC[(size_t)c * ((size_t)(nn + 1) * 16) + (size_t)nn * 16 + j] = (_Float16)0.f;
    }
}

// ---------------- MFMA dense transform: H = X @ W, CHUNKED output ----------------
template <int NO, bool SCALE, typename XT>
__global__ __launch_bounds__(256) void gemm_mfma_k(const XT* __restrict__ X,
                                                   const _Float16* __restrict__ WT,
                                                   const float* __restrict__ dinv,
                                                   _Float16* __restrict__ H, int nrows) {
    constexpr int K = 128;
    constexpr int NCT = NO / 16;
    int wv = (int)((blockIdx.x * (size_t)blockDim.x + threadIdx.x) >> 6);
    int r0 = wv * 16;
    if (r0 >= nrows) return;
    int lane = threadIdx.x & 63;
    int lr = lane & 15;          // A-row / D-col
    int kg = lane >> 4;          // k-group
    int rg = r0 + lr;
    if (rg >= nrows) rg = nrows - 1;   // clamp (stores are guarded)
    size_t cs = (size_t)(nrows + 1) * 16;    // chunk stride (incl. dummy row)

    half8 a[4];
    if constexpr (std::is_same<XT, float>::value) {
#pragma unroll
        for (int ks = 0; ks < 4; ks++) {
            const float* px = X + (size_t)rg * K + ks * 32 + kg * 8;
            float4 x0 = *(const float4*)px;
            float4 x1 = *(const float4*)(px + 4);
            half8 vv;
            vv[0] = (_Float16)x0.x; vv[1] = (_Float16)x0.y;
            vv[2] = (_Float16)x0.z; vv[3] = (_Float16)x0.w;
            vv[4] = (_Float16)x1.x; vv[5] = (_Float16)x1.y;
            vv[6] = (_Float16)x1.z; vv[7] = (_Float16)x1.w;
            a[ks] = vv;
        }
    } else {
#pragma unroll
        for (int ks = 0; ks < 4; ks++)
            a[ks] = *(const half8*)(X + (size_t)rg * K + ks * 32 + kg * 8);
    }

    f32x4 acc[NCT];
#pragma unroll
    for (int ct = 0; ct < NCT; ct++) acc[ct] = (f32x4){0.f, 0.f, 0.f, 0.f};
#pragma unroll
    for (int ct = 0; ct < NCT; ct++) {
#pragma unroll
        for (int ks = 0; ks < 4; ks++) {
            half8 b = *(const half8*)(WT + (size_t)(ct * 16 + lr) * K + ks * 32 + kg * 8);
            acc[ct] = __builtin_amdgcn_mfma_f32_16x16x32_f16(a[ks], b, acc[ct], 0, 0, 0);
        }
    }
#pragma unroll
    for (int i = 0; i < 4; i++) {
        int rr = r0 + kg * 4 + i;
        if (rr < nrows) {
            float s = SCALE ? dinv[rr] : 1.f;
            _Float16* hp = H + (size_t)rr * 16 + lr;
#pragma unroll
            for (int ct = 0; ct < NCT; ct++)
                hp[ct * cs] = (_Float16)(acc[ct][i] * s);
        }
    }
}

// ---------------- chunked aggregation v3: group-per-node, lanes own FEATURES ----------------
// HC[c][node][16] fp16, slice 3.2MB -> XCD-L2-resident via chunk=blockIdx%NCHUNK (many short blocks).
// Wave = 8 nodes x 8 lanes. Lane owns 2 features (half2): row gather = 8 lanes x 4B = one 32B
// segment (8 coherent segments/instruction). No cross-lane reduction. 4 edges/iter via
// group-uniform int4 csr load (pad4 segments, dummy src=nn -> zero row) -> 32 gathers in flight.
template <int NF, int NCHUNK, bool RELU, bool OUTSCALE, typename OutT>
__global__ __launch_bounds__(256) void aggc3_k(const __half* __restrict__ HC,
                                               const int* __restrict__ rowbeg,
                                               const int* __restrict__ rend,
                                               const int* __restrict__ csr,
                                               const float* __restrict__ dinv,
                                               const float* __restrict__ bias,
                                               OutT* __restrict__ Out, int nn) {
    constexpr int CF = 16;
    int chunk = (int)(blockIdx.x % NCHUNK);
    int ngrp = (int)(blockIdx.x / NCHUNK);
    int t = threadIdx.x;
    int li = t & 7;                  // feature-pair index within node group
    int nid = ngrp * 32 + (t >> 3);  // 32 nodes per block (8 per wave)
    if (nid >= nn) return;
    const __half* Hc = HC + (size_t)chunk * ((size_t)(nn + 1) * CF) + li * 2;

    float ax = 0.f, ay = 0.f;
    int i = rowbeg[nid], end = rend[nid];
    for (; i < end; i += 4) {
        int4 s4 = *(const int4*)(csr + i);   // group-uniform (8 lanes same addr)
        __half2 v0 = *(const __half2*)(Hc + (size_t)s4.x * CF);
        __half2 v1 = *(const __half2*)(Hc + (size_t)s4.y * CF);
        __half2 v2 = *(const __half2*)(Hc + (size_t)s4.z * CF);
        __half2 v3 = *(const __half2*)(Hc + (size_t)s4.w * CF);
        __half2 p01 = __hadd2(v0, v1);       // one fp16 pair-add level
        __half2 p23 = __hadd2(v2, v3);
        float2 f01 = __half22float2(p01);
        float2 f23 = __half22float2(p23);
        ax += f01.x + f23.x;
        ay += f01.y + f23.y;
    }
    // self-loop (h'[nid], already dinv-scaled)
    __half2 hs = *(const __half2*)(Hc + (size_t)nid * CF);
    float2 fs = __half22float2(hs);
    float dn = dinv[nid];
    const float2 b2v = *(const float2*)(bias + chunk * CF + li * 2);
    float rx = (ax + fs.x) * dn + b2v.x;
    float ry = (ay + fs.y) * dn + b2v.y;
    if (RELU) { rx = fmaxf(rx, 0.f); ry = fmaxf(ry, 0.f); }
    if (OUTSCALE) { rx *= dn; ry *= dn; }
    if constexpr (std::is_same<OutT, __half>::value) {
        *(__half2*)(Out + (size_t)nid * NF + chunk * CF + li * 2) = __floats2half2_rn(rx, ry);
    } else {
        float2 o; o.x = rx; o.y = ry;
        *(float2*)(Out + (size_t)nid * NF + chunk * CF + li * 2) = o;
    }
}

// ---------------- launch ----------------

extern "C" void kernel_launch(void* const* d_in, const int* in_sizes, int n_in,
                              void* d_out, int out_size, void* d_ws, size_t ws_size,
                              hipStream_t stream) {
    const float* x  = (const float*)d_in[0];
    const int* ei   = (const int*)d_in[1];
    const float* W1 = (const float*)d_in[2];
    const float* b1 = (const float*)d_in[3];
    const float* W2 = (const float*)d_in[4];
    const float* b2 = (const float*)d_in[5];
    float* out = (float*)d_out;

    const int IN = 128, HID = 128;
    int nn = in_sizes[0] / IN;     // 100000
    int ne = in_sizes[1] / 2;      // 1600000
    const int* src = ei;
    const int* dst = ei + ne;
    int nbuckets = (nn + NPB - 1) / NPB;   // 196 (<= NBK)

    char* w = (char*)d_ws;
    size_t off = 0;
    auto take = [&](size_t bytes) -> void* {
        void* p = w + off;
        off = (off + bytes + 255) & ~(size_t)255;
        return p;
    };
    int*      gcount = (int*)take(NBK * 4);
    int*      gbase  = (int*)take(NBK * 4);
    int*      cursor = (int*)take(NBK * 4);
    int*      rowbeg = (int*)take((size_t)nn * 4);
    int*      rend   = (int*)take((size_t)nn * 4);
    float*    dinv   = (float*)take((size_t)nn * 4);
    int*      csr    = (int*)take(((size_t)ne + NBK * 1540) * 4);   // padded CSR
    _Float16* WT1    = (_Float16*)take(128 * 128 * 2);
    _Float16* WT2    = (_Float16*)take(64 * 128 * 2);
    _Float16* hC     = (_Float16*)take((size_t)(nn + 1) * 128 * 2); // 8 x [nn+1][16]
    __half*   h1     = (__half*)take((size_t)nn * HID * 2);         // row-major
    _Float16* h2C    = hC;                 // reuse: hC dead after agg1 (4 x [nn+1][16])
    int*      bucketed = (int*)hC;         // reuse: dead before prepW/gemm1 touch hC

    (void)ws_size; (void)n_in; (void)out_size;

    hipMemsetAsync(gcount, 0, NBK * 4, stream);

    int tb = 256;
    histA_k<<<(ne + 4095) / 4096, 256, 0, stream>>>(dst, ne, gcount);
    scanB_k<<<1, NBK, 0, stream>>>(gcount, gbase, cursor);
    partA_k<<<(ne + 8191) / 8192, 512, 0, stream>>>(src, dst, cursor, bucketed, ne);
    csrB_k<<<nbuckets, 1024, 0, stream>>>(bucketed, gbase, gcount, csr, rowbeg, rend, dinv, nn);
    prepW_k<<<(128 * 128 + 128 * 64 + 128 + tb - 1) / tb, tb, 0, stream>>>(W1, W2, WT1, WT2, hC, nn);

    int gblocks = ((nn + 15) / 16 + 3) / 4;   // 1 wave per 16 rows, 4 waves/block
    int ngrp32 = (nn + 31) / 32;              // node groups of 32 for aggc3

    // layer 1: hC = dinv .* (x @ W1)  [fp16, chunked] ; h1 = dinv .* relu(agg(hC) + b1)
    gemm_mfma_k<128, true, float><<<gblocks, tb, 0, stream>>>(x, WT1, dinv, hC, nn);
    aggc3_k<128, 8, true, true, __half><<<ngrp32 * 8, tb, 0, stream>>>(
        (const __half*)hC, rowbeg, rend, csr, dinv, b1, h1, nn);

    // layer 2: h2C = h1 @ W2 (already dinv-scaled)  [chunked] ; out = agg(h2C) + b2  [fp32]
    gemm_mfma_k<64, false, __half><<<gblocks, tb, 0, stream>>>(h1, WT2, dinv, h2C, nn);
    aggc3_k<64, 4, false, false, float><<<ngrp32 * 4, tb, 0, stream>>>(
        (const __half*)h2C, rowbeg, rend, csr, dinv, b2, out, nn);
}